// Round 8
// baseline (158.622 us; speedup 1.0000x reference)
//
#include <hip/hip_runtime.h>
#include <cstdint>
#include <cstddef>

#define B 4096
#define D 128
#define MARGIN_F 0.2f
#define CW 256            // per-row candidate capacity

typedef short bf16x8 __attribute__((ext_vector_type(8)));
typedef float f32x4 __attribute__((ext_vector_type(4)));

// order-preserving float->uint (ascending uint == ascending float)
__device__ __forceinline__ uint32_t xform_key(float f) {
    uint32_t u = __float_as_uint(f);
    return u ^ (uint32_t)((((int32_t)u) >> 31) | 0x80000000);
}
// decode 16-bit truncated key (bucket center under round-to-nearest encode)
__device__ __forceinline__ float unxform16(uint32_t k16) {
    uint32_t u = k16 << 16;
    u = (u & 0x80000000u) ? (u ^ 0x80000000u) : ~u;
    return __uint_as_float(u);
}
__device__ __forceinline__ unsigned short f2bf(float f) {   // round-nearest-even
    uint32_t u = __float_as_uint(f);
    return (unsigned short)((u + 0x7FFFu + ((u >> 16) & 1u)) >> 16);
}

// sq[i] = ||R[i]||^2 (fp32); block 0 also zeroes the output scalar
__global__ __launch_bounds__(256) void sq_kernel(const float* __restrict__ R,
                                                 float* __restrict__ sq,
                                                 float* __restrict__ out) {
    if (blockIdx.x == 0 && threadIdx.x == 0) out[0] = 0.0f;
    int wave = threadIdx.x >> 6;
    int lane = threadIdx.x & 63;
    int row  = blockIdx.x * 4 + wave;
    const float2* R2 = (const float2*)R + (size_t)row * (D / 2);
    float2 v = R2[lane];
    float s = v.x * v.x + v.y * v.y;
#pragma unroll
    for (int off = 32; off > 0; off >>= 1) s += __shfl_down(s, off);
    if (lane == 0) sq[row] = s;
}

// R (fp32) -> Rb (bf16 rne), row-major 4096x128
__global__ __launch_bounds__(256) void conv_kernel(const float* __restrict__ R,
                                                   unsigned short* __restrict__ Rb) {
    int idx = (blockIdx.x * 256 + threadIdx.x) * 4;
    float4 v = *(const float4*)(R + idx);
    ushort4 o;
    o.x = f2bf(v.x); o.y = f2bf(v.y); o.z = f2bf(v.z); o.w = f2bf(v.w);
    *(ushort4*)(Rb + idx) = o;
}

// bf16 MFMA gram + dist/margin -> 16-bit keys. Direct global fragment loads
// (Rb is 1MB, L2-resident), wave-private epilogue LDS, ZERO barriers.
__global__ __launch_bounds__(256) void gemm_sim_v3(const unsigned short* __restrict__ Rb,
                                                   const float* __restrict__ sq,
                                                   const int* __restrict__ labels,
                                                   unsigned short* __restrict__ simk) {
    __shared__ unsigned short sEP[4][4608];   // 36KB: per-wave 64x72 transpose pad

    const int tid  = threadIdx.x;
    const int wid  = tid >> 6, lane = tid & 63;
    const int q    = lane >> 4, t = lane & 15;
    const int Ay0  = blockIdx.y * 128;
    const int Bx0  = blockIdx.x * 128;
    const int m0   = (wid >> 1) * 64;
    const int n0   = (wid & 1) * 64;

    f32x4 acc[4][4];
#pragma unroll
    for (int mi = 0; mi < 4; ++mi)
#pragma unroll
        for (int ni = 0; ni < 4; ++ni) acc[mi][ni] = (f32x4)0.0f;

    const unsigned short* baseA = Rb + (size_t)(Ay0 + m0 + t) * D + q * 8;
    const unsigned short* baseB = Rb + (size_t)(Bx0 + n0 + t) * D + q * 8;

#pragma unroll
    for (int kq = 0; kq < 4; ++kq) {
        bf16x8 af[4], bfr[4];
#pragma unroll
        for (int mi = 0; mi < 4; ++mi)
            af[mi] = *(const bf16x8*)(baseA + (size_t)mi * 16 * D + kq * 32);
#pragma unroll
        for (int ni = 0; ni < 4; ++ni)
            bfr[ni] = *(const bf16x8*)(baseB + (size_t)ni * 16 * D + kq * 32);
#pragma unroll
        for (int mi = 0; mi < 4; ++mi)
#pragma unroll
            for (int ni = 0; ni < 4; ++ni)
                acc[mi][ni] = __builtin_amdgcn_mfma_f32_16x16x32_bf16(
                    af[mi], bfr[ni], acc[mi][ni], 0, 0, 0);
    }

    // epilogue: keys -> wave-private LDS [64][72], then full-line stores
    float sqc[4]; int lc[4];
#pragma unroll
    for (int ni = 0; ni < 4; ++ni) {
        sqc[ni] = sq[Bx0 + n0 + ni * 16 + t];
        lc[ni]  = labels[Bx0 + n0 + ni * 16 + t];
    }
#pragma unroll
    for (int mi = 0; mi < 4; ++mi) {
#pragma unroll
        for (int r = 0; r < 4; ++r) {
            int lrow = mi * 16 + q * 4 + r;            // C/D: row = q*4+r
            int grow = Ay0 + m0 + lrow;
            float sqr = sq[grow];
            int   lr  = labels[grow];
#pragma unroll
            for (int ni = 0; ni < 4; ++ni) {
                float g  = acc[mi][ni][r];
                float d2 = fmaxf(sqr + sqc[ni] - 2.0f * g, 0.0f);
                float dist = (d2 > 0.0f) ? sqrtf(d2) : 0.0f;
                float s = -dist + ((lr == lc[ni]) ? 0.0f : MARGIN_F);
                uint32_t key = xform_key(s);           // sim <= 0.2 -> no ovf on +0x8000
                sEP[wid][lrow * 72 + ni * 16 + t] =
                    (unsigned short)((key + 0x8000u) >> 16);
            }
        }
    }
#pragma unroll
    for (int it = 0; it < 8; ++it) {
        int rr = it * 8 + (lane >> 3);
        int cc = (lane & 7) * 8;
        uint4 v = *(uint4*)(&sEP[wid][rr * 72 + cc]);
        *(uint4*)(simk + (size_t)(Ay0 + m0 + rr) * B + Bx0 + n0 + cc) = v;
    }
}

// ONE WAVE PER BLOCK, one row per block (grid 4096): max residency, k-tail
// load-balance. comb = (u16<<12)|(4095-j) makes every rank compare 1 v_cmp.
__global__ __launch_bounds__(64, 4) void row_loss_w64(const unsigned short* __restrict__ simk,
                                                      const int* __restrict__ labels,
                                                      float* __restrict__ out) {
    __shared__ uint32_t cand_c[CW];   // comb | (match<<31)
    __shared__ int cnt;

    const int lane = threadIdx.x;
    const int row  = blockIdx.x;
    if (lane == 0) cnt = 0;

    const uint4* pv = (const uint4*)(simk + (size_t)row * B);
    const int4*  lv = (const int4*)labels;
    const int li = labels[row];

    // element e = q*8+c lives at j = (q*64+lane)*8 + c
    uint4 kv[8];
    uint64_t mbits = 0;
    uint32_t t1 = 0, t2 = 0;
#pragma unroll
    for (int q = 0; q < 8; ++q) {
        kv[q] = pv[q * 64 + lane];
        const int lb = (q * 64 + lane) * 2;
        int4 la = lv[lb], lc = lv[lb + 1];
        uint32_t u[8] = {kv[q].x & 0xFFFFu, kv[q].x >> 16,
                         kv[q].y & 0xFFFFu, kv[q].y >> 16,
                         kv[q].z & 0xFFFFu, kv[q].z >> 16,
                         kv[q].w & 0xFFFFu, kv[q].w >> 16};
#pragma unroll
        for (int c = 0; c < 8; ++c) {
            uint32_t mn = min(t1, u[c]);
            t1 = max(t1, u[c]);
            t2 = max(t2, mn);
        }
        mbits |= (uint64_t)(la.x == li) << (q * 8 + 0);
        mbits |= (uint64_t)(la.y == li) << (q * 8 + 1);
        mbits |= (uint64_t)(la.z == li) << (q * 8 + 2);
        mbits |= (uint64_t)(la.w == li) << (q * 8 + 3);
        mbits |= (uint64_t)(lc.x == li) << (q * 8 + 4);
        mbits |= (uint64_t)(lc.y == li) << (q * 8 + 5);
        mbits |= (uint64_t)(lc.z == li) << (q * 8 + 6);
        mbits |= (uint64_t)(lc.w == li) << (q * 8 + 7);
    }

    int kloc = __popcll(mbits);
#pragma unroll
    for (int off = 32; off > 0; off >>= 1) kloc += __shfl_xor(kloc, off);
    const int k = kloc;
    const float kf = (float)k;

    // ballot binary search: T = k-th largest of the 128-subset (<= true k-th)
    const int kneed = min(k, 128);
    uint32_t T = 0;
#pragma unroll
    for (int b = 15; b >= 0; --b) {
        uint32_t g = T | (1u << b);
        int c = __popcll(__ballot(t1 >= g)) + __popcll(__ballot(t2 >= g));
        if (c >= kneed) T = g;
    }
    const uint32_t combT = T << 12;

    // gather candidates = {u >= T} U {matches}; comb = (u<<12)|(4095-j)
#pragma unroll
    for (int q = 0; q < 8; ++q) {
        uint32_t u[8] = {kv[q].x & 0xFFFFu, kv[q].x >> 16,
                         kv[q].y & 0xFFFFu, kv[q].y >> 16,
                         kv[q].z & 0xFFFFu, kv[q].z >> 16,
                         kv[q].w & 0xFFFFu, kv[q].w >> 16};
        int jb = (q * 64 + lane) * 8;
#pragma unroll
        for (int c = 0; c < 8; ++c) {
            int e = q * 8 + c;
            uint32_t m = (uint32_t)((mbits >> e) & 1);
            if (u[c] >= T || m) {
                int p = atomicAdd(&cnt, 1);
                if (p < CW)
                    cand_c[p] = (u[c] << 12) | (uint32_t)(4095 - (jb + c)) | (m << 31);
            }
        }
    }
    const int ncand = min(cnt, CW);   // lgkmcnt wait ordered after this wave's atomics

    float facc = 0.0f;

    // candidate-internal exact ranks for u >= T (every beater is a candidate)
    for (int s = lane; s < ncand; s += 64) {
        uint32_t cs = cand_c[s];
        uint32_t comb = cs & 0x7FFFFFFFu;
        int m = (int)(cs >> 31);
        if (comb >= combT) {
            int c2 = 0;
            for (int c = 0; c < ncand; ++c)
                c2 += ((cand_c[c] & 0x7FFFFFFFu) > comb) ? 1 : 0;
            int rank = 1 + c2;
            float v = unxform16(comb >> 12);
            if (!m && rank <= k)
                facc += v * (0.5f + ((kf - (float)rank + 1.0f) / kf) * 0.5f);
            else if (m && rank > k)
                facc -= v * (0.5f + (((float)rank - kf) / (float)(B - k)) * 0.5f);
        }
    }

    // below-T matches (rank > k guaranteed): global scans, batch 4 per pass
    uint32_t p0 = 0xFFFFFFFFu, p1 = 0xFFFFFFFFu, p2 = 0xFFFFFFFFu, p3 = 0xFFFFFFFFu;
    int np = 0;
    for (int c = 0; c <= ncand; ++c) {
        bool flushit = (c == ncand);
        if (!flushit) {
            uint32_t cc_ = cand_c[c];
            if ((cc_ & 0x80000000u) && (cc_ & 0x7FFFFFFFu) < combT) {
                uint32_t comb = cc_ & 0x7FFFFFFFu;
                if (np == 0) p0 = comb; else if (np == 1) p1 = comb;
                else if (np == 2) p2 = comb; else p3 = comb;
                ++np;
                flushit = (np == 4);
            }
        }
        if (flushit && np > 0) {
            int c0 = 0, c1 = 0, c2 = 0, c3 = 0;
#pragma unroll
            for (int q = 0; q < 8; ++q) {
                uint32_t u[8] = {kv[q].x & 0xFFFFu, kv[q].x >> 16,
                                 kv[q].y & 0xFFFFu, kv[q].y >> 16,
                                 kv[q].z & 0xFFFFu, kv[q].z >> 16,
                                 kv[q].w & 0xFFFFu, kv[q].w >> 16};
                int jb = (q * 64 + lane) * 8;
#pragma unroll
                for (int cc = 0; cc < 8; ++cc) {
                    uint32_t comb_e = (u[cc] << 12) | (uint32_t)(4095 - (jb + cc));
                    c0 += (comb_e > p0) ? 1 : 0;
                    c1 += (comb_e > p1) ? 1 : 0;
                    c2 += (comb_e > p2) ? 1 : 0;
                    c3 += (comb_e > p3) ? 1 : 0;
                }
            }
#pragma unroll
            for (int off = 32; off > 0; off >>= 1) {
                c0 += __shfl_xor(c0, off); c1 += __shfl_xor(c1, off);
                c2 += __shfl_xor(c2, off); c3 += __shfl_xor(c3, off);
            }
            if (lane == 0) {
                int rk[4] = {1 + c0, 1 + c1, 1 + c2, 1 + c3};
                uint32_t pp[4] = {p0, p1, p2, p3};
                for (int i = 0; i < np; ++i) {
                    float v = unxform16(pp[i] >> 12);
                    facc -= v * (0.5f + (((float)rk[i] - kf) / (float)(B - k)) * 0.5f);
                }
            }
            p0 = p1 = p2 = p3 = 0xFFFFFFFFu;
            np = 0;
        }
    }

#pragma unroll
    for (int off = 32; off > 0; off >>= 1) facc += __shfl_xor(facc, off);
    if (lane == 0) atomicAdd(out, facc);
}

extern "C" void kernel_launch(void* const* d_in, const int* in_sizes, int n_in,
                              void* d_out, int out_size, void* d_ws, size_t ws_size,
                              hipStream_t stream) {
    const float* R      = (const float*)d_in[0];
    const int*   labels = (const int*)d_in[1];
    float* out = (float*)d_out;

    float*          sq   = (float*)d_ws;                                     // 16 KB
    unsigned short* Rb   = (unsigned short*)((char*)d_ws + 16 * 1024);       // 1 MB
    unsigned short* simk = (unsigned short*)((char*)d_ws + 16 * 1024 + 1024 * 1024 + 256);

    hipLaunchKernelGGL(sq_kernel, dim3(B / 4), dim3(256), 0, stream, R, sq, out);
    hipLaunchKernelGGL(conv_kernel, dim3(B * D / 1024), dim3(256), 0, stream, R, Rb);
    hipLaunchKernelGGL(gemm_sim_v3, dim3(B / 128, B / 128), dim3(256), 0, stream,
                       Rb, sq, labels, simk);
    hipLaunchKernelGGL(row_loss_w64, dim3(B), dim3(64), 0, stream, simk, labels, out);
}